// Round 3
// baseline (611.447 us; speedup 1.0000x reference)
//
#include <hip/hip_runtime.h>

// Fused LocalSelfAttention (Swin ws=8, nh=16, hd=32), B=16 N=4096 C=512.
// v3: occupancy restructure — 2 blocks/CU.
//   - LDS 114K -> 80K exactly (xw 64K + scr 16K) => 2 blocks/CU, 4 waves/SIMD.
//     Stall-bound diagnosis (v2): 1 block/CU left >70% of cycles with no pipe
//     issuing; second resident block overlaps weight-load latency + barriers.
//   - 16 passes, 1 head/pass, all 8 waves co-op: wave w -> token-tile tw=w&3,
//     role g=w>>2 (g0 produces q(ct0,ct1)+k(ct0); g1 k(ct1)+v(ct0,ct1)).
//   - scr (16KB): q[64][32] | K[64][32] | vT[32][64] | ob[64][32], all with
//     bijective XOR swizzles giving <=2-way bank conflicts on b128 reads.
//   - S^T = K.Q^T (keys in-lane): softmax = 15 fmax + 2 shfl; P-fragments for
//     PV built by intra-wave __shfl (no P staging, no extra barrier).
//   - proj fused per pass as K=32 chunk (kk == head); pacc in regs (64 VGPR).
//   - 2 barriers/pass (33 total): s1 (stores->attn reads), s3 (ob->proj).
//     WAR hazards proven covered by s3(p-1)/s1(p+1).
//   - __launch_bounds__(512,4) caps VGPR at 128 for 2-block residency.

typedef short s16x8 __attribute__((ext_vector_type(8)));
typedef float f32x4 __attribute__((ext_vector_type(4)));

union V8 { uint4 u4; uint2 u2[2]; s16x8 h; ushort s[8]; uint u[4]; };

__device__ __forceinline__ ushort f2b(float f) {
    union { float f; uint u; } v; v.f = f;
    return (ushort)((v.u + 0x7fffu + ((v.u >> 16) & 1u)) >> 16);  // RNE
}
// 8 fp32 -> 8 bf16 (1 v_perm per pair)
__device__ __forceinline__ void cvt8(const float* __restrict__ p, V8& d) {
    union { float4 f; uint u[4]; } a, b;
    a.f = *(const float4*)p;  b.f = *(const float4*)(p + 4);
    d.u[0] = __builtin_amdgcn_perm(a.u[1], a.u[0], 0x07060302u);
    d.u[1] = __builtin_amdgcn_perm(a.u[3], a.u[2], 0x07060302u);
    d.u[2] = __builtin_amdgcn_perm(b.u[1], b.u[0], 0x07060302u);
    d.u[3] = __builtin_amdgcn_perm(b.u[3], b.u[2], 0x07060302u);
}
__device__ __forceinline__ f32x4 mfma16(s16x8 a, s16x8 b, f32x4 c) {
    return __builtin_amdgcn_mfma_f32_16x16x32_bf16(a, b, c, 0, 0, 0);
}
__device__ __forceinline__ uint2 pack4(float a, float b, float c, float d) {
    uint2 r;
    r.x = (uint)f2b(a) | ((uint)f2b(b) << 16);
    r.y = (uint)f2b(c) | ((uint)f2b(d) << 16);
    return r;
}

// ---------------------------------------------------------------------------
// Prologue: fp32 weights -> bf16 in MFMA-fragment order (unchanged from v2).
// qkv tiles 0..95 (mat*32+ntile) at ws[0..786432); proj tiles 0..31 at
// ws[786432..1048576). Per (tile,kk): 512-short block, element
// (quad*128 + colw*8 + j) = w[n=tile*16+colw][k=kk*32+quad*8+j].
// ---------------------------------------------------------------------------
__global__ __launch_bounds__(256)
void pack_w(const float* __restrict__ wqkv, const float* __restrict__ wproj,
            ushort* __restrict__ dst)
{
    const int gid = blockIdx.x * 256 + threadIdx.x;   // 131072 threads
    const int o = gid << 3;
    const int colw = (o >> 3) & 15, quad = (o >> 7) & 3, kk = (o >> 9) & 15;
    const int tile = o >> 13;
    const float* src;
    if (o < 786432) {
        const int mat = tile >> 5, nt = tile & 31;
        src = wqkv + (size_t)(mat * 512 + nt * 16 + colw) * 512 + (kk << 5) + (quad << 3);
    } else {
        const int nt = tile - 96;
        src = wproj + (size_t)(nt * 16 + colw) * 512 + (kk << 5) + (quad << 3);
    }
    float4 a = *(const float4*)src, b = *(const float4*)(src + 4);
    V8 v;
    v.s[0] = f2b(a.x); v.s[1] = f2b(a.y); v.s[2] = f2b(a.z); v.s[3] = f2b(a.w);
    v.s[4] = f2b(b.x); v.s[5] = f2b(b.y); v.s[6] = f2b(b.z); v.s[7] = f2b(b.w);
    *(uint4*)(dst + o) = v.u4;
}

// ---------------------------------------------------------------------------
// Fused kernel. PK=true: packed bf16 weights in ws. PK=false: fp32 fallback.
// ---------------------------------------------------------------------------
template<bool PK>
__global__ __launch_bounds__(512, 4)
void win_fused(const float* __restrict__ x, const void* __restrict__ Wq,
               const void* __restrict__ Wp, const float* __restrict__ bproj,
               float* __restrict__ out)
{
    __shared__ __align__(16) ushort xw[64 * 512];  // 65536 B, swizzled A-tile
    __shared__ __align__(16) ushort scr[8192];     // 16384 B: q|K|vT|ob

    char* const sb = (char*)scr;
    constexpr int QO = 0, KO = 4096, VO = 8192, OO = 12288;  // byte offsets

    const int tid  = threadIdx.x;
    const int lane = tid & 63;
    const int wave = tid >> 6;          // 0..7
    const int tw   = wave & 3;          // token-tile (16 tokens) = q-tile
    const int g    = wave >> 2;         // role: 0=q+k0 producer, 1=k1+v; PV d-tile
    const int col  = lane & 15, quad = lane >> 4;
    const int win  = blockIdx.x;
    const int bb = win >> 6, wh = (win >> 3) & 7, ww = win & 7;
    const size_t xbase = (size_t)(bb * 4096) * 512;

    // ---------------- gather (scrambled window partition), fp32 -> bf16 ------
    {
        const int m8  = tid & 63;
        const int u8  = tid >> 6;
        const int t   = ((m8 & 7) << 3) | (m8 >> 3);
        const int ch0 = m8 << 3;
        const float* gp = x + xbase + (size_t)(wh * 512 + u8 * 64 + ww * 8) * 512 + ch0;
        V8 L[8];
        #pragma unroll
        for (int du = 0; du < 8; ++du) cvt8(gp + du * 512, L[du]);
        #pragma unroll
        for (int e = 0; e < 8; ++e) {
            V8 W;
            #pragma unroll
            for (int du = 0; du < 8; ++du) W.s[du] = L[du].s[e];
            const int c8 = (e << 3) | u8;
            *(uint4*)(&xw[(t << 9) + ((c8 ^ (t & 7)) << 3)]) = W.u4;
        }
    }
    __syncthreads();

    f32x4 pacc[4][4];                   // proj accumulator: 4 tok-tiles x 4 out-tiles
    #pragma unroll
    for (int mt = 0; mt < 4; ++mt)
        #pragma unroll
        for (int nt = 0; nt < 4; ++nt) pacc[mt][nt] = (f32x4){0.f, 0.f, 0.f, 0.f};

    const int swq = ((col >> 1) & 3) << 4;   // q/K/ob read swizzle (rows = *16+col)
    const int swv = (col & 7) << 4;          // vT swizzle (d = *16+col)

    for (int h = 0; h < 16; ++h) {
        // ---- GEMM1: 3 output tiles per wave (M=16 tok, K=512) ----
        f32x4 c0 = {0.f,0.f,0.f,0.f}, c1 = {0.f,0.f,0.f,0.f}, c2 = {0.f,0.f,0.f,0.f};
        int bt0, bt1, bt2;
        const float *w0 = nullptr, *w1 = nullptr, *w2 = nullptr;
        if (g == 0) { bt0 = h*2; bt1 = h*2+1; bt2 = 32+h*2; }          // q0,q1,k0
        else        { bt0 = 32+h*2+1; bt1 = 64+h*2; bt2 = 64+h*2+1; }  // k1,v0,v1
        if constexpr (!PK) {
            const float* W = (const float*)Wq;
            const int r0 = g ? (512+h*32+16)  : (h*32);
            const int r1 = g ? (1024+h*32)    : (h*32+16);
            const int r2 = g ? (1024+h*32+16) : (512+h*32);
            w0 = W + (size_t)(r0+col)*512; w1 = W + (size_t)(r1+col)*512;
            w2 = W + (size_t)(r2+col)*512;
        }
        #pragma unroll 2
        for (int kk = 0; kk < 16; ++kk) {
            const int t = (tw << 4) | col, c8 = (kk << 2) | quad;
            V8 av; av.u4 = *(const uint4*)(&xw[(t << 9) + ((c8 ^ (t & 7)) << 3)]);
            V8 b0, b1, b2;
            if constexpr (PK) {
                const ushort* W = (const ushort*)Wq;
                const int lo = lane << 3;
                b0.u4 = *(const uint4*)(&W[(size_t)(bt0*16 + kk)*512 + lo]);
                b1.u4 = *(const uint4*)(&W[(size_t)(bt1*16 + kk)*512 + lo]);
                b2.u4 = *(const uint4*)(&W[(size_t)(bt2*16 + kk)*512 + lo]);
            } else {
                cvt8(w0 + (kk << 5) + (quad << 3), b0);
                cvt8(w1 + (kk << 5) + (quad << 3), b1);
                cvt8(w2 + (kk << 5) + (quad << 3), b2);
            }
            c0 = mfma16(av.h, b0.h, c0);
            c1 = mfma16(av.h, b1.h, c1);
            c2 = mfma16(av.h, b2.h, c2);
        }
        // stores are WAR-safe vs pass p-1 reads: those ended before s3(p-1).

        // ---- stage q/K/vT (scalar u16, swizzled; <=4-way on stores) ----
        #pragma unroll
        for (int r = 0; r < 4; ++r) {
            const int tok  = (tw << 4) + (quad << 2) + r;
            const int st   = ((tok >> 1) & 3) << 4;
            const int rowb = tok << 6;
            if (g == 0) {
                *(ushort*)(sb + QO + rowb + ((col*2)      ^ st)) = f2b(c0[r]);
                *(ushort*)(sb + QO + rowb + ((32 + col*2) ^ st)) = f2b(c1[r]);
                *(ushort*)(sb + KO + rowb + ((col*2)      ^ st)) = f2b(c2[r]);
            } else {
                *(ushort*)(sb + KO + rowb + ((32 + col*2) ^ st)) = f2b(c0[r]);
                *(ushort*)(sb + VO + col*128        + ((tok*2) ^ swv)) = f2b(c1[r]);
                *(ushort*)(sb + VO + (16+col)*128   + ((tok*2) ^ swv)) = f2b(c2[r]);
            }
        }
        __syncthreads();   // s1: q/K/vT visible

        // ---- S^T = K . Q^T (A=K 4 key-tiles, B=own q-tile, K-dim=hd=32) ----
        s16x8 kf0, kf1, kf2, kf3; V8 qf;
        {
            V8 v0, v1, v2, v3;
            v0.u4 = *(const uint4*)(sb + KO + ((0*16+col) << 6) + ((quad << 4) ^ swq));
            v1.u4 = *(const uint4*)(sb + KO + ((1*16+col) << 6) + ((quad << 4) ^ swq));
            v2.u4 = *(const uint4*)(sb + KO + ((2*16+col) << 6) + ((quad << 4) ^ swq));
            v3.u4 = *(const uint4*)(sb + KO + ((3*16+col) << 6) + ((quad << 4) ^ swq));
            kf0 = v0.h; kf1 = v1.h; kf2 = v2.h; kf3 = v3.h;
            qf.u4 = *(const uint4*)(sb + QO + (((tw<<4)+col) << 6) + ((quad << 4) ^ swq));
        }
        f32x4 ST[4];
        ST[0] = mfma16(kf0, qf.h, (f32x4){0.f,0.f,0.f,0.f});
        ST[1] = mfma16(kf1, qf.h, (f32x4){0.f,0.f,0.f,0.f});
        ST[2] = mfma16(kf2, qf.h, (f32x4){0.f,0.f,0.f,0.f});
        ST[3] = mfma16(kf3, qf.h, (f32x4){0.f,0.f,0.f,0.f});

        // ---- softmax: 16 keys in-lane + cross-quad shfl; inv deferred ----
        const float smul = 0.17677669529663689f * 1.4426950408889634f;  // scale*log2e
        float m0 = ST[0][0];
        #pragma unroll
        for (int a = 0; a < 4; ++a)
            #pragma unroll
            for (int r = 0; r < 4; ++r) m0 = fmaxf(m0, ST[a][r]);
        m0 = fmaxf(m0, __shfl_xor(m0, 16));
        m0 = fmaxf(m0, __shfl_xor(m0, 32));
        float s0 = 0.f;
        #pragma unroll
        for (int a = 0; a < 4; ++a)
            #pragma unroll
            for (int r = 0; r < 4; ++r) {
                const float pv = exp2f((ST[a][r] - m0) * smul);
                ST[a][r] = pv; s0 += pv;
            }
        s0 += __shfl_xor(s0, 16);
        s0 += __shfl_xor(s0, 32);
        const float inv = 1.0f / s0;

        // ---- P fragments via intra-wave shuffle; PV (dtile = g) ----
        const uint2 pk0 = pack4(ST[0][0], ST[0][1], ST[0][2], ST[0][3]);
        const uint2 pk1 = pack4(ST[1][0], ST[1][1], ST[1][2], ST[1][3]);
        const uint2 pk2 = pack4(ST[2][0], ST[2][1], ST[2][2], ST[2][3]);
        const uint2 pk3 = pack4(ST[3][0], ST[3][1], ST[3][2], ST[3][3]);
        const int srcA = ((quad & 1) << 5) + col;   // quads 2*(quad&1), +1 of same col
        const int srcB = srcA + 16;
        const bool hi = quad >= 2;                  // key-tile select within kh
        f32x4 OT = {0.f,0.f,0.f,0.f};
        {   // kh=0: keys 0..31 (tiles 0,1)
            const uint a0x = __shfl((int)pk0.x, srcA), a0y = __shfl((int)pk0.y, srcA);
            const uint b0x = __shfl((int)pk0.x, srcB), b0y = __shfl((int)pk0.y, srcB);
            const uint a1x = __shfl((int)pk1.x, srcA), a1y = __shfl((int)pk1.y, srcA);
            const uint b1x = __shfl((int)pk1.x, srcB), b1y = __shfl((int)pk1.y, srcB);
            V8 pf;
            pf.u[0] = hi ? a1x : a0x;  pf.u[1] = hi ? a1y : a0y;
            pf.u[2] = hi ? b1x : b0x;  pf.u[3] = hi ? b1y : b0y;
            V8 vf; vf.u4 = *(const uint4*)(sb + VO + (((g<<4)+col) << 7)
                                           + (((quad << 4)) ^ swv));
            OT = mfma16(vf.h, pf.h, OT);
        }
        {   // kh=1: keys 32..63 (tiles 2,3)
            const uint a0x = __shfl((int)pk2.x, srcA), a0y = __shfl((int)pk2.y, srcA);
            const uint b0x = __shfl((int)pk2.x, srcB), b0y = __shfl((int)pk2.y, srcB);
            const uint a1x = __shfl((int)pk3.x, srcA), a1y = __shfl((int)pk3.y, srcA);
            const uint b1x = __shfl((int)pk3.x, srcB), b1y = __shfl((int)pk3.y, srcB);
            V8 pf;
            pf.u[0] = hi ? a1x : a0x;  pf.u[1] = hi ? a1y : a0y;
            pf.u[2] = hi ? b1x : b0x;  pf.u[3] = hi ? b1y : b0y;
            V8 vf; vf.u4 = *(const uint4*)(sb + VO + (((g<<4)+col) << 7)
                                           + ((64 + (quad << 4)) ^ swv));
            OT = mfma16(vf.h, pf.h, OT);
        }

        // ---- o (scaled) -> ob[64 tok][32 ch]; rows are tw*16+col ----
        {
            const int rowb = ((tw << 4) + col) << 6;
            #pragma unroll
            for (int r = 0; r < 4; ++r) {
                const int ch = (g << 4) + (quad << 2) + r;
                *(ushort*)(sb + OO + rowb + ((ch*2) ^ swq)) = f2b(OT[r] * inv);
            }
        }
        __syncthreads();   // s3: ob complete (also fences vT/K/q reads)

        // ---- proj partial: K-chunk = head h (kk == h), N-slice = wave*64 ----
        {
            V8 a0, a1, a2_, a3;
            a0.u4  = *(const uint4*)(sb + OO + ((0*16+col) << 6) + ((quad << 4) ^ swq));
            a1.u4  = *(const uint4*)(sb + OO + ((1*16+col) << 6) + ((quad << 4) ^ swq));
            a2_.u4 = *(const uint4*)(sb + OO + ((2*16+col) << 6) + ((quad << 4) ^ swq));
            a3.u4  = *(const uint4*)(sb + OO + ((3*16+col) << 6) + ((quad << 4) ^ swq));
            #pragma unroll
            for (int nt = 0; nt < 4; ++nt) {
                s16x8 b;
                if constexpr (PK) {
                    const ushort* W = (const ushort*)Wp;
                    V8 v; v.u4 = *(const uint4*)(&W[(size_t)(((wave<<2)+nt)*16 + h)*512
                                                    + (lane << 3)]);
                    b = v.h;
                } else {
                    const float* W = (const float*)Wp;
                    V8 v; cvt8(W + (size_t)((wave<<6) + (nt<<4) + col)*512
                                 + (h << 5) + (quad << 3), v);
                    b = v.h;
                }
                pacc[0][nt] = mfma16(a0.h,  b, pacc[0][nt]);
                pacc[1][nt] = mfma16(a1.h,  b, pacc[1][nt]);
                pacc[2][nt] = mfma16(a2_.h, b, pacc[2][nt]);
                pacc[3][nt] = mfma16(a3.h,  b, pacc[3][nt]);
            }
        }
        // no barrier: next pass's q/K/vT stores are fenced by s3 (reads of
        // pass p ended before it); ob WAR covered by s1 of pass p+1.
    }

    // ---------------- epilogue: bias + fp32 out at merged positions ----------
    const size_t wbase = (size_t)(bb * 4096 + wh * 512 + ww * 8) * 512;
    #pragma unroll
    for (int nt = 0; nt < 4; ++nt) {
        const int cg = (wave << 6) + (nt << 4) + col;
        const float bias = bproj[cg];
        #pragma unroll
        for (int mt = 0; mt < 4; ++mt)
            #pragma unroll
            for (int r = 0; r < 4; ++r) {
                const int t = (mt << 4) + (quad << 2) + r;
                const size_t go = wbase + (size_t)(((t >> 3) << 6) + (t & 7)) * 512;
                out[go + cg] = pacc[mt][nt][r] + bias;
            }
    }
}

extern "C" void kernel_launch(void* const* d_in, const int* in_sizes, int n_in,
                              void* d_out, int out_size, void* d_ws, size_t ws_size,
                              hipStream_t stream) {
    const float* x     = (const float*)d_in[0];
    const float* wqkv  = (const float*)d_in[1];
    const float* wproj = (const float*)d_in[2];
    const float* bproj = (const float*)d_in[3];
    float* out = (float*)d_out;
    (void)in_sizes; (void)n_in; (void)out_size;

    if (ws_size >= 2097152) {
        ushort* wpk = (ushort*)d_ws;
        pack_w<<<dim3(512), dim3(256), 0, stream>>>(wqkv, wproj, wpk);
        win_fused<true><<<dim3(1024), dim3(512), 0, stream>>>(
            x, wpk, wpk + 786432, bproj, out);
    } else {
        win_fused<false><<<dim3(1024), dim3(512), 0, stream>>>(
            x, wqkv, wproj, bproj, out);
    }
}

// Round 4
// 428.402 us; speedup vs baseline: 1.4273x; 1.4273x over previous
//
#include <hip/hip_runtime.h>

// Fused LocalSelfAttention (Swin ws=8, nh=16, hd=32), B=16 N=4096 C=512.
// v4: fragment-traffic + barrier restructure. 1024-thr block = 1 window.
//   - 4 passes x 4 heads. GEMM1 wave = (head hh, m-half mh, n-half nhf):
//     2x3 register tile -> per kk: 2 A(LDS) + 3 B(global) : 6 MFMA
//     (0.83 KB/MFMA vs v3 1.33; qkv B traffic 6 MB -> 3 MB per block).
//   - attention wave = (head, q-tile): S^T = K.Q^T once (no v3 2x redundancy),
//     both d-halves of PV; softmax in-lane (15 fmax + 2 shfl), inv deferred.
//   - proj fused per pass (K-chunk = 128 ch), B-frags loaded once per block.
//   - 9 barriers per block (vs v3 2x33 per CU): gather + {s1, s3} x 4 passes.
//   - LDS 128 KB: xw 64K | per-head q4K,k4K,vT4K x4 | ob 16K. 16 waves = 4/SIMD.
//   - All LDS swizzles re-derived: q/k linear-64B rows + ((tok>>2)&3)<<4 XOR
//     (reads optimal, stores <=4-way; v3's staging was 8-way — the 1.8e7
//     bank-conflict source); vT/ob verified <=2-way both sides.
//   - epilogue stores both 64B halves of each 128B line back-to-back.

typedef short s16x8 __attribute__((ext_vector_type(8)));
typedef float f32x4 __attribute__((ext_vector_type(4)));

union V8 { uint4 u4; uint2 u2[2]; s16x8 h; ushort s[8]; uint u[4]; };

__device__ __forceinline__ ushort f2b(float f) {
    union { float f; uint u; } v; v.f = f;
    return (ushort)((v.u + 0x7fffu + ((v.u >> 16) & 1u)) >> 16);  // RNE
}
__device__ __forceinline__ void cvt8(const float* __restrict__ p, V8& d) {
    union { float4 f; uint u[4]; } a, b;
    a.f = *(const float4*)p;  b.f = *(const float4*)(p + 4);
    d.u[0] = __builtin_amdgcn_perm(a.u[1], a.u[0], 0x07060302u);
    d.u[1] = __builtin_amdgcn_perm(a.u[3], a.u[2], 0x07060302u);
    d.u[2] = __builtin_amdgcn_perm(b.u[1], b.u[0], 0x07060302u);
    d.u[3] = __builtin_amdgcn_perm(b.u[3], b.u[2], 0x07060302u);
}
__device__ __forceinline__ f32x4 mfma16(s16x8 a, s16x8 b, f32x4 c) {
    return __builtin_amdgcn_mfma_f32_16x16x32_bf16(a, b, c, 0, 0, 0);
}
__device__ __forceinline__ uint2 pack4(float a, float b, float c, float d) {
    uint2 r;
    r.x = (uint)f2b(a) | ((uint)f2b(b) << 16);
    r.y = (uint)f2b(c) | ((uint)f2b(d) << 16);
    return r;
}

// ---------------------------------------------------------------------------
// Prologue: fp32 weights -> bf16 in MFMA-fragment order (unchanged).
// qkv tiles 0..95 (mat*32+ntile) at ws[0..786432); proj tiles 0..31 at
// ws[786432..1048576). Per (tile,kk): 512-short block, element
// (quad*128 + colw*8 + j) = w[n=tile*16+colw][k=kk*32+quad*8+j].
// ---------------------------------------------------------------------------
__global__ __launch_bounds__(256)
void pack_w(const float* __restrict__ wqkv, const float* __restrict__ wproj,
            ushort* __restrict__ dst)
{
    const int gid = blockIdx.x * 256 + threadIdx.x;   // 131072 threads
    const int o = gid << 3;
    const int colw = (o >> 3) & 15, quad = (o >> 7) & 3, kk = (o >> 9) & 15;
    const int tile = o >> 13;
    const float* src;
    if (o < 786432) {
        const int mat = tile >> 5, nt = tile & 31;
        src = wqkv + (size_t)(mat * 512 + nt * 16 + colw) * 512 + (kk << 5) + (quad << 3);
    } else {
        const int nt = tile - 96;
        src = wproj + (size_t)(nt * 16 + colw) * 512 + (kk << 5) + (quad << 3);
    }
    float4 a = *(const float4*)src, b = *(const float4*)(src + 4);
    V8 v;
    v.s[0] = f2b(a.x); v.s[1] = f2b(a.y); v.s[2] = f2b(a.z); v.s[3] = f2b(a.w);
    v.s[4] = f2b(b.x); v.s[5] = f2b(b.y); v.s[6] = f2b(b.z); v.s[7] = f2b(b.w);
    *(uint4*)(dst + o) = v.u4;
}

// ---------------------------------------------------------------------------
// Fused kernel. PK=true: packed bf16 weights in ws. PK=false: fp32 fallback.
// ---------------------------------------------------------------------------
template<bool PK>
__global__ __launch_bounds__(1024, 4)
void win_fused(const float* __restrict__ x, const void* __restrict__ Wq,
               const void* __restrict__ Wp, const float* __restrict__ bproj,
               float* __restrict__ out)
{
    __shared__ __align__(16) ushort xw[32768];   // 64 KB window A-tile (swizzled)
    __shared__ __align__(16) ushort scr[32768];  // 64 KB: 4x{q,k,vT} 12K + ob 16K

    char* const sb = (char*)scr;
    // per-head hh base = hh*12288: q[tok][32d] @+0, k @+4096, vT[32d][64tok] @+8192
    // ob[64 tok][128 ch] @ 49152
    const int tid  = threadIdx.x;
    const int lane = tid & 63;
    const int wave = tid >> 6;           // 0..15
    const int col  = lane & 15, quad = lane >> 4;
    const int win  = blockIdx.x;
    const int bb = win >> 6, wh = (win >> 3) & 7, ww = win & 7;
    const size_t xbase = (size_t)(bb * 4096) * 512;

    // ---------------- gather (scrambled window partition), fp32 -> bf16 ------
    {
        const int m8 = lane;              // channel-oct
        const int u8 = wave & 7;          // spatial row in window
        const int dh = wave >> 3;         // du half (0: du 0..3, 1: du 4..7)
        const int t  = ((m8 & 7) << 3) | (m8 >> 3);
        const int ch0 = m8 << 3;
        const float* gp = x + xbase
            + (size_t)(wh * 512 + u8 * 64 + ww * 8 + dh * 4) * 512 + ch0;
        V8 L[4];
        #pragma unroll
        for (int i = 0; i < 4; ++i) cvt8(gp + i * 512, L[i]);
        #pragma unroll
        for (int e = 0; e < 8; ++e) {
            union { uint2 u; ushort s[4]; } Wv;
            #pragma unroll
            for (int i = 0; i < 4; ++i) Wv.s[i] = L[i].s[e];
            const int c8 = (e << 3) | u8;
            *(uint2*)(&xw[(t << 9) + ((c8 ^ (t & 7)) << 3) + (dh << 2)]) = Wv.u;
        }
    }
    __syncthreads();

    const int hhg = wave >> 2;           // head-in-pass (GEMM1 + attn + ob)
    const int mh  = (wave >> 1) & 1;     // GEMM1 m-half
    const int nhf = wave & 1;            // GEMM1 n-half
    const int tw  = wave & 3;            // attention q-tile

    f32x4 pacc[4][2];                    // proj acc: 4 tok-tiles x 2 n-tiles
    #pragma unroll
    for (int mt = 0; mt < 4; ++mt) {
        pacc[mt][0] = (f32x4){0.f, 0.f, 0.f, 0.f};
        pacc[mt][1] = (f32x4){0.f, 0.f, 0.f, 0.f};
    }

    for (int p = 0; p < 4; ++p) {
        const int h = (p << 2) | hhg;

        // ---- GEMM1: M=32 (2 m-tiles) x N=48 (3 n-16cols), K=512 ----
        f32x4 c00 = {0.f,0.f,0.f,0.f}, c01 = {0.f,0.f,0.f,0.f}, c02 = {0.f,0.f,0.f,0.f};
        f32x4 c10 = {0.f,0.f,0.f,0.f}, c11 = {0.f,0.f,0.f,0.f}, c12 = {0.f,0.f,0.f,0.f};
        size_t wb0 = 0, wb1 = 0, wb2 = 0;
        const float *f0 = nullptr, *f1 = nullptr, *f2 = nullptr;
        if constexpr (PK) {
            if (nhf == 0) { wb0 = (size_t)(2*h)   * 8192; wb1 = (size_t)(2*h+1)  * 8192;
                            wb2 = (size_t)(32+2*h)* 8192; }
            else          { wb0 = (size_t)(32+2*h+1)*8192; wb1 = (size_t)(64+2*h)*8192;
                            wb2 = (size_t)(64+2*h+1)*8192; }
        } else {
            const float* W = (const float*)Wq;
            if (nhf == 0) {
                f0 = W + (size_t)(h*32 + col) * 512;
                f1 = W + (size_t)(h*32 + 16 + col) * 512;
                f2 = W + (size_t)(512 + h*32 + col) * 512;
            } else {
                f0 = W + (size_t)(512 + h*32 + 16 + col) * 512;
                f1 = W + (size_t)(1024 + h*32 + col) * 512;
                f2 = W + (size_t)(1024 + h*32 + 16 + col) * 512;
            }
        }
        #pragma unroll 2
        for (int kk = 0; kk < 16; ++kk) {
            const int c8 = (kk << 2) | quad;
            V8 a0, a1;
            { const int t = mh*32 + col;      a0.u4 = *(const uint4*)(&xw[(t << 9) + ((c8 ^ (t & 7)) << 3)]); }
            { const int t = mh*32 + 16 + col; a1.u4 = *(const uint4*)(&xw[(t << 9) + ((c8 ^ (t & 7)) << 3)]); }
            V8 b0, b1, b2;
            if constexpr (PK) {
                const ushort* W = (const ushort*)Wq;
                const int lo = (kk << 9) + (lane << 3);
                b0.u4 = *(const uint4*)(&W[wb0 + lo]);
                b1.u4 = *(const uint4*)(&W[wb1 + lo]);
                b2.u4 = *(const uint4*)(&W[wb2 + lo]);
            } else {
                cvt8(f0 + (kk << 5) + (quad << 3), b0);
                cvt8(f1 + (kk << 5) + (quad << 3), b1);
                cvt8(f2 + (kk << 5) + (quad << 3), b2);
            }
            c00 = mfma16(a0.h, b0.h, c00);
            c01 = mfma16(a0.h, b1.h, c01);
            c02 = mfma16(a0.h, b2.h, c02);
            c10 = mfma16(a1.h, b0.h, c10);
            c11 = mfma16(a1.h, b1.h, c11);
            c12 = mfma16(a1.h, b2.h, c12);
        }

        // ---- stage q/k (scalar u16) + vT (uint2) into head region ----
        // q/k byte(tok,d) = tok*64 + ((d*2) ^ (((tok>>2)&3)<<4)); here
        // (tok>>2)&3 == quad for our tokens.  vT byte(d,tok) = d*128 +
        // ((tok*2) ^ ((d&7)<<4)).
        {
            const int hb = hhg * 12288;
            #pragma unroll
            for (int mt = 0; mt < 2; ++mt) {
                const int tokb = mh*32 + mt*16 + (quad << 2);
                const f32x4& d0 = mt ? c10 : c00;
                const f32x4& d1 = mt ? c11 : c01;
                const f32x4& d2 = mt ? c12 : c02;
                if (nhf == 0) {
                    #pragma unroll
                    for (int r = 0; r < 4; ++r) {
                        const int rowb = hb + ((tokb + r) << 6);
                        *(ushort*)(sb + rowb + ((col*2)      ^ (quad << 4))) = f2b(d0[r]);
                        *(ushort*)(sb + rowb + ((32 + col*2) ^ (quad << 4))) = f2b(d1[r]);
                        *(ushort*)(sb + 4096 + rowb + ((col*2) ^ (quad << 4))) = f2b(d2[r]);
                    }
                } else {
                    #pragma unroll
                    for (int r = 0; r < 4; ++r) {
                        const int rowb = hb + ((tokb + r) << 6);
                        *(ushort*)(sb + 4096 + rowb + ((32 + col*2) ^ (quad << 4))) = f2b(d0[r]);
                    }
                    const int tsw = (tokb * 2) ^ ((col & 7) << 4);
                    *(uint2*)(sb + hb + 8192 + col * 128 + tsw) =
                        pack4(d1[0], d1[1], d1[2], d1[3]);
                    *(uint2*)(sb + hb + 8192 + (16 + col) * 128 + tsw) =
                        pack4(d2[0], d2[1], d2[2], d2[3]);
                }
            }
        }
        __syncthreads();   // s1: q/k/vT of all 4 heads visible

        // ---- S^T = K . Q^T (4 key-tiles x own q-tile), K-dim = 32 ----
        const int ab = hhg * 12288;
        const int sr = ((col >> 2) & 3) << 4;
        V8 kf0, kf1, kf2, kf3, qf;
        kf0.u4 = *(const uint4*)(sb + ab + 4096 + ((0*16 + col) << 6) + ((quad << 4) ^ sr));
        kf1.u4 = *(const uint4*)(sb + ab + 4096 + ((1*16 + col) << 6) + ((quad << 4) ^ sr));
        kf2.u4 = *(const uint4*)(sb + ab + 4096 + ((2*16 + col) << 6) + ((quad << 4) ^ sr));
        kf3.u4 = *(const uint4*)(sb + ab + 4096 + ((3*16 + col) << 6) + ((quad << 4) ^ sr));
        qf.u4  = *(const uint4*)(sb + ab + (((tw << 4) + col) << 6) + ((quad << 4) ^ sr));
        f32x4 ST[4];
        ST[0] = mfma16(kf0.h, qf.h, (f32x4){0.f,0.f,0.f,0.f});
        ST[1] = mfma16(kf1.h, qf.h, (f32x4){0.f,0.f,0.f,0.f});
        ST[2] = mfma16(kf2.h, qf.h, (f32x4){0.f,0.f,0.f,0.f});
        ST[3] = mfma16(kf3.h, qf.h, (f32x4){0.f,0.f,0.f,0.f});

        // ---- softmax (keys in-lane across kt,r; cross-quad shfl) ----
        const float smul = 0.17677669529663689f * 1.4426950408889634f;  // scale*log2e
        float m0 = ST[0][0];
        #pragma unroll
        for (int a = 0; a < 4; ++a)
            #pragma unroll
            for (int r = 0; r < 4; ++r) m0 = fmaxf(m0, ST[a][r]);
        m0 = fmaxf(m0, __shfl_xor(m0, 16));
        m0 = fmaxf(m0, __shfl_xor(m0, 32));
        float s0 = 0.f;
        #pragma unroll
        for (int a = 0; a < 4; ++a)
            #pragma unroll
            for (int r = 0; r < 4; ++r) {
                const float pv = exp2f((ST[a][r] - m0) * smul);
                ST[a][r] = pv; s0 += pv;
            }
        s0 += __shfl_xor(s0, 16);
        s0 += __shfl_xor(s0, 32);
        const float inv = 1.0f / s0;

        // ---- PV: both d-halves; P-frags via intra-wave shuffle ----
        const uint2 pk0 = pack4(ST[0][0], ST[0][1], ST[0][2], ST[0][3]);
        const uint2 pk1 = pack4(ST[1][0], ST[1][1], ST[1][2], ST[1][3]);
        const uint2 pk2 = pack4(ST[2][0], ST[2][1], ST[2][2], ST[2][3]);
        const uint2 pk3 = pack4(ST[3][0], ST[3][1], ST[3][2], ST[3][3]);
        const int srcA = ((quad & 1) << 5) + col;
        const int srcB = srcA + 16;
        const bool hi = quad >= 2;
        f32x4 OT0 = {0.f,0.f,0.f,0.f}, OT1 = {0.f,0.f,0.f,0.f};
        const int vsw = (col & 7) << 4;
        {   // kh=0: keys 0..31
            const uint a0x = __shfl((int)pk0.x, srcA), a0y = __shfl((int)pk0.y, srcA);
            const uint b0x = __shfl((int)pk0.x, srcB), b0y = __shfl((int)pk0.y, srcB);
            const uint a1x = __shfl((int)pk1.x, srcA), a1y = __shfl((int)pk1.y, srcA);
            const uint b1x = __shfl((int)pk1.x, srcB), b1y = __shfl((int)pk1.y, srcB);
            V8 pf;
            pf.u[0] = hi ? a1x : a0x;  pf.u[1] = hi ? a1y : a0y;
            pf.u[2] = hi ? b1x : b0x;  pf.u[3] = hi ? b1y : b0y;
            V8 vf0, vf1;
            vf0.u4 = *(const uint4*)(sb + ab + 8192 + ((0*16 + col) << 7) + (((quad << 4)) ^ vsw));
            vf1.u4 = *(const uint4*)(sb + ab + 8192 + ((16 + col) << 7)   + (((quad << 4)) ^ vsw));
            OT0 = mfma16(vf0.h, pf.h, OT0);
            OT1 = mfma16(vf1.h, pf.h, OT1);
        }
        {   // kh=1: keys 32..63
            const uint a0x = __shfl((int)pk2.x, srcA), a0y = __shfl((int)pk2.y, srcA);
            const uint b0x = __shfl((int)pk2.x, srcB), b0y = __shfl((int)pk2.y, srcB);
            const uint a1x = __shfl((int)pk3.x, srcA), a1y = __shfl((int)pk3.y, srcA);
            const uint b1x = __shfl((int)pk3.x, srcB), b1y = __shfl((int)pk3.y, srcB);
            V8 pf;
            pf.u[0] = hi ? a1x : a0x;  pf.u[1] = hi ? a1y : a0y;
            pf.u[2] = hi ? b1x : b0x;  pf.u[3] = hi ? b1y : b0y;
            V8 vf0, vf1;
            vf0.u4 = *(const uint4*)(sb + ab + 8192 + ((0*16 + col) << 7) + ((64 + (quad << 4)) ^ vsw));
            vf1.u4 = *(const uint4*)(sb + ab + 8192 + ((16 + col) << 7)   + ((64 + (quad << 4)) ^ vsw));
            OT0 = mfma16(vf0.h, pf.h, OT0);
            OT1 = mfma16(vf1.h, pf.h, OT1);
        }

        // ---- o (scaled) -> ob[64 tok][128 ch]; byte = tok*256 + (ch*2 ^ (tok&3)<<5)
        {
            const int rowb = 49152 + (((tw << 4) + col) << 8);
            const int osw = (col & 3) << 5;
            const int ch2a = hhg*64 + (quad << 3);          // dt=0: (ch0*2)
            *(uint2*)(sb + rowb + (ch2a ^ osw)) =
                pack4(OT0[0]*inv, OT0[1]*inv, OT0[2]*inv, OT0[3]*inv);
            *(uint2*)(sb + rowb + ((ch2a + 32) ^ osw)) =
                pack4(OT1[0]*inv, OT1[1]*inv, OT1[2]*inv, OT1[3]*inv);
        }
        __syncthreads();   // s3: ob complete (also fences q/k/vT reads)

        // ---- proj partial: K-chunk = pass's 128 ch; wave owns 32 out cols ----
        #pragma unroll 2
        for (int kkl = 0; kkl < 4; ++kkl) {
            const int kkg = (p << 2) | kkl;
            V8 a0, a1, a2, a3;
            const int cb = ((kkl << 6) + (quad << 4));
            const int osw = (col & 3) << 5;
            a0.u4 = *(const uint4*)(sb + 49152 + ((0*16 + col) << 8) + (cb ^ osw));
            a1.u4 = *(const uint4*)(sb + 49152 + ((1*16 + col) << 8) + (cb ^ osw));
            a2.u4 = *(const uint4*)(sb + 49152 + ((2*16 + col) << 8) + (cb ^ osw));
            a3.u4 = *(const uint4*)(sb + 49152 + ((3*16 + col) << 8) + (cb ^ osw));
            #pragma unroll
            for (int nt = 0; nt < 2; ++nt) {
                s16x8 b;
                if constexpr (PK) {
                    const ushort* W = (const ushort*)Wp;
                    V8 v; v.u4 = *(const uint4*)(&W[(size_t)(((wave*2 + nt)*16) + kkg) * 512
                                                    + (lane << 3)]);
                    b = v.h;
                } else {
                    const float* W = (const float*)Wp;
                    V8 v; cvt8(W + (size_t)(wave*32 + nt*16 + col) * 512
                                 + (kkg << 5) + (quad << 3), v);
                    b = v.h;
                }
                pacc[0][nt] = mfma16(a0.h, b, pacc[0][nt]);
                pacc[1][nt] = mfma16(a1.h, b, pacc[1][nt]);
                pacc[2][nt] = mfma16(a2.h, b, pacc[2][nt]);
                pacc[3][nt] = mfma16(a3.h, b, pacc[3][nt]);
            }
        }
        // no extra barrier: next pass's staging writes occur after s3 (program
        // order), and every wave reaches s1(p+1) only after its proj reads.
    }

    // ---------------- epilogue: bias + fp32 out at merged positions ----------
    // both 64B halves of each 128B line stored back-to-back (write-combine).
    const size_t wbase = (size_t)(bb * 4096 + wh * 512 + ww * 8) * 512;
    const float bv0 = bproj[wave*32 + col];
    const float bv1 = bproj[wave*32 + 16 + col];
    #pragma unroll
    for (int mt = 0; mt < 4; ++mt)
        #pragma unroll
        for (int r = 0; r < 4; ++r) {
            const int t = (mt << 4) + (quad << 2) + r;
            float* op = out + wbase + (size_t)(((t >> 3) << 6) + (t & 7)) * 512
                        + wave*32;
            op[col]      = pacc[mt][0][r] + bv0;
            op[16 + col] = pacc[mt][1][r] + bv1;
        }
}

extern "C" void kernel_launch(void* const* d_in, const int* in_sizes, int n_in,
                              void* d_out, int out_size, void* d_ws, size_t ws_size,
                              hipStream_t stream) {
    const float* x     = (const float*)d_in[0];
    const float* wqkv  = (const float*)d_in[1];
    const float* wproj = (const float*)d_in[2];
    const float* bproj = (const float*)d_in[3];
    float* out = (float*)d_out;
    (void)in_sizes; (void)n_in; (void)out_size;

    if (ws_size >= 2097152) {
        ushort* wpk = (ushort*)d_ws;
        pack_w<<<dim3(512), dim3(256), 0, stream>>>(wqkv, wproj, wpk);
        win_fused<true><<<dim3(1024), dim3(1024), 0, stream>>>(
            x, wpk, wpk + 786432, bproj, out);
    } else {
        win_fused<false><<<dim3(1024), dim3(1024), 0, stream>>>(
            x, wqkv, wproj, bproj, out);
    }
}